// Round 9
// baseline (226.873 us; speedup 1.0000x reference)
//
#include <hip/hip_runtime.h>
#include <math.h>

#define ALPHA 26
#define TPB 256
#define ROWF 26                  // stage row stride in floats (token row)
#define WAVEF (64 * ROWF)        // 1664 floats per wave-private region
#define BUFF (4 * WAVEF)         // 6656 floats per block (single buffer, 26.6 KB)
#define NBLK 2048                // persistent blocks, 2 balanced tiles each

typedef __attribute__((ext_vector_type(8))) short short8;
typedef __attribute__((ext_vector_type(4))) float float4v;
typedef __attribute__((ext_vector_type(2))) float float2v;

__device__ __forceinline__ unsigned short f2bf(float f) {
    unsigned u = __builtin_bit_cast(unsigned, f);
    u += 0x7FFFu + ((u >> 16) & 1u);          // round-to-nearest-even
    return (unsigned short)(u >> 16);
}

// DPP row_ror:N within each 16-lane row (VALU pipe, no LDS traffic).
template<int CTRL>
__device__ __forceinline__ float rorf(float v) {
    int s = __builtin_bit_cast(int, v);
    int d = __builtin_amdgcn_update_dpp(s, s, CTRL, 0xf, 0xf, false);
    return __builtin_bit_cast(float, d);
}

// Pre-kernel: row-L2-normalize rotor, emit TRANSPOSED bf16 B matrix padded to
// 32x32: rnbT[n][k] = bf16(rotor[k][n]/||rotor[k]||) for k,n<26, else 0.
__global__ void rotor_norm_kernel(const float* __restrict__ rotor,
                                  unsigned short* __restrict__ rnbT) {
    __shared__ float inv[32];
    const int t = threadIdx.x;            // 64 threads
    if (t < 32) {
        float s = 0.f;
        if (t < ALPHA) {
            #pragma unroll
            for (int j = 0; j < ALPHA; ++j) {
                float v = rotor[t * ALPHA + j];
                s += v * v;
            }
            inv[t] = 1.0f / sqrtf(s);
        } else {
            inv[t] = 0.f;
        }
    }
    __syncthreads();
    const int n  = t >> 1;                // 0..31
    const int k0 = (t & 1) * 16;          // 0 or 16
    #pragma unroll
    for (int kk = 0; kk < 16; ++kk) {
        const int k = k0 + kk;
        float v = (k < ALPHA && n < ALPHA) ? rotor[k * ALPHA + n] * inv[k] : 0.f;
        rnbT[n * 32 + k] = f2bf(v);
    }
}

// R8 structure with ONE change: input loads are NON-TEMPORAL.
// Evidence: store instruction streams identical to R0's gave W=104 MiB
// (ideal) when input was DMA-staged (R0/R3) but 199 MB when input was
// loaded through L2 (R8). The input has zero reuse (each line read once);
// normal loads allocating 104 MB of dead lines in L2/L3 is pure pollution
// that manufactures extra HBM write traffic. nt loads (slc) skip the
// allocation. nt STORES remain banned (R5/R7: ~1.8x write amplification).
__global__ __launch_bounds__(TPB, 6) void rotor_main(
        const float* __restrict__ x,
        const unsigned short* __restrict__ rnbT,
        float* __restrict__ out,
        int ntiles) {
    __shared__ float stage[BUFF];         // 26624 B -> 6 blocks/CU fit

    const int tid  = threadIdx.x;
    const int lane = tid & 63;
    const int wave = tid >> 6;
    const int n15  = lane & 15;
    const int quad = lane >> 4;
    const int waveF = wave * WAVEF;

    // ---- B fragments: two contiguous 16B loads from transposed rnbT ----
    // B-operand layout (16x16x32): n = lane&15, k = quad*8 + j.
    short8 bf0 = *(const short8*)(rnbT + n15 * 32 + quad * 8);
    short8 bf1 = *(const short8*)(rnbT + (n15 + 16) * 32 + quad * 8);

    int tile = blockIdx.x;
    if (tile >= ntiles) return;
    const int stride = gridDim.x;

    // Per-wave tile slice: 64 tokens x 26 floats = 26 dwords/lane in regs.
    float4v r[6]; float2v r2;
    auto ldregs = [&](int t) {
        const float* gp = x + (long long)t * (TPB * ALPHA) + waveF;
        #pragma unroll
        for (int it = 0; it < 6; ++it)
            r[it] = __builtin_nontemporal_load(
                        (const float4v*)(gp + it * 256 + lane * 4));
        r2 = __builtin_nontemporal_load(
                        (const float2v*)(gp + 1536 + lane * 2));
    };

    ldregs(tile);

    int i = 0;
    for (; tile < ntiles; tile += stride, ++i) {
        // ---- Stage current tile regs -> LDS (7 vector ds_writes) ----
        {
            float* lp = &stage[waveF];
            #pragma unroll
            for (int it = 0; it < 6; ++it)
                *(float4v*)(lp + it * 256 + lane * 4) = r[it];
            *(float2v*)(lp + 1536 + lane * 2) = r2;
        }
        const int tnext = tile + stride;
        if (tnext < ntiles) ldregs(tnext);     // T14: issue early, consume at
                                               // next iteration's stage-in

        const int tokBase = tile * TPB + wave * 64;

        // ---- GEMM: 4 M-tiles x 2 N-tiles of mfma_f32_16x16x32_bf16 ----
        float4v accA[4], accB[4];
        #pragma unroll
        for (int m = 0; m < 4; ++m) {
            accA[m] = (float4v){0.f, 0.f, 0.f, 0.f};
            accB[m] = (float4v){0.f, 0.f, 0.f, 0.f};
        }

        #pragma unroll
        for (int m = 0; m < 4; ++m) {
            // A layout: this lane supplies token m*16 + n15, k = quad*8 + j.
            const int tok = tokBase + m * 16 + n15;
            const int r_ = (tok & 8191) % 26;         // S = 8192, position == 1
            const int rowOff = waveF + (m * 16 + n15) * ROWF;
            const int k0 = quad * 8;
            int idx0 = k0 - r_; if (idx0 < 0) idx0 += 26;   // in [0,25]

            short8 af;
            #pragma unroll
            for (int j = 0; j < 8; ++j) {
                int idx = idx0 + j; if (idx >= 26) idx -= 26;  // stays in [0,25]
                // No K-pad mask needed: rnbT rows k>=26 are exact zeros.
                af[j] = (short)f2bf(stage[rowOff + idx]);
            }
            accA[m] = __builtin_amdgcn_mfma_f32_16x16x32_bf16(af, bf0, accA[m], 0, 0, 0);
            accB[m] = __builtin_amdgcn_mfma_f32_16x16x32_bf16(af, bf1, accB[m], 0, 0, 0);
        }

        // ---- In-register softmax (DPP rotate-reduce over the 16-lane row).
        // Lane (n15,quad) holds token m*16+quad*4+rg, features n15 / n15+16.
        // Padded cols 26..31 are exact zeros: excluded from sum; max(real,0)
        // leaves softmax invariant. Scatter results to wave-private LDS
        // (2-way bank aliasing only = free), then stream out coalesced.
        #pragma unroll
        for (int m = 0; m < 4; ++m) {
            #pragma unroll
            for (int rg = 0; rg < 4; ++rg) {
                float a = accA[m][rg];
                float b = accB[m][rg];
                float mx = fmaxf(a, b);
                mx = fmaxf(mx, rorf<0x121>(mx));
                mx = fmaxf(mx, rorf<0x122>(mx));
                mx = fmaxf(mx, rorf<0x124>(mx));
                mx = fmaxf(mx, rorf<0x128>(mx));
                float ea = __expf(a - mx);
                float eb = (n15 < ALPHA - 16) ? __expf(b - mx) : 0.f;
                float s = ea + eb;
                s += rorf<0x121>(s);
                s += rorf<0x122>(s);
                s += rorf<0x124>(s);
                s += rorf<0x128>(s);
                float inv = 1.0f / s;
                const int base = waveF + (m * 16 + quad * 4 + rg) * ROWF;
                stage[base + n15] = ea * inv;
                if (n15 < ALPHA - 16)
                    stage[base + 16 + n15] = eb * inv;
            }
        }

        // ---- Coalesced plain stores (L2-routed, write-combined) ----
        float* gout = out + (long long)tile * (TPB * ALPHA) + waveF;
        #pragma unroll
        for (int it = 0; it < 6; ++it) {
            float4v d = *(const float4v*)&stage[waveF + it * 256 + lane * 4];
            *(float4v*)(gout + it * 256 + lane * 4) = d;
        }
        {
            float2v d = *(const float2v*)&stage[waveF + 1536 + lane * 2];
            *(float2v*)(gout + 1536 + lane * 2) = d;
        }
    }
}

extern "C" void kernel_launch(void* const* d_in, const int* in_sizes, int n_in,
                              void* d_out, int out_size, void* d_ws, size_t ws_size,
                              hipStream_t stream) {
    const float* x     = (const float*)d_in[0];   // [128, 8192, 26] fp32
    const float* rotor = (const float*)d_in[1];   // [26, 26] fp32
    float* out = (float*)d_out;                   // [128, 8192, 26] fp32
    unsigned short* rnbT = (unsigned short*)d_ws; // bf16 B^T matrix, 32x32 = 2 KB

    rotor_norm_kernel<<<1, 64, 0, stream>>>(rotor, rnbT);

    const int tokens = out_size / ALPHA;          // 1,048,576
    const int tiles  = tokens / TPB;              // 4096
    const int grid   = (tiles < NBLK) ? tiles : NBLK;
    rotor_main<<<grid, TPB, 0, stream>>>(x, rnbT, out, tiles);
}

// Round 10
// 202.141 us; speedup vs baseline: 1.1223x; 1.1223x over previous
//
#include <hip/hip_runtime.h>
#include <math.h>

#define ALPHA 26
#define TPB 256
#define ROWF 26                  // stage row stride in floats (token row)
#define WAVEF (64 * ROWF)        // 1664 floats per wave-private region
#define BUFF (4 * WAVEF)         // 6656 floats per block-wide buffer
#define NBLK 768                 // 3 blocks/CU * 256 CUs (LDS dbuf residency)

typedef __attribute__((ext_vector_type(8))) short short8;
typedef __attribute__((ext_vector_type(4))) float float4v;
typedef __attribute__((address_space(3))) float lds_f;
typedef const __attribute__((address_space(1))) float glb_f;

__device__ __forceinline__ unsigned short f2bf(float f) {
    unsigned u = __builtin_bit_cast(unsigned, f);
    u += 0x7FFFu + ((u >> 16) & 1u);          // round-to-nearest-even
    return (unsigned short)(u >> 16);
}

// DPP row_ror:N within each 16-lane row (VALU pipe, no LDS traffic).
template<int CTRL>
__device__ __forceinline__ float rorf(float v) {
    int s = __builtin_bit_cast(int, v);
    int d = __builtin_amdgcn_update_dpp(s, s, CTRL, 0xf, 0xf, false);
    return __builtin_bit_cast(float, d);
}

// Pre-kernel: row-L2-normalize rotor, emit TRANSPOSED bf16 B matrix padded to
// 32x32: rnbT[n][k] = bf16(rotor[k][n]/||rotor[k]||) for k,n<26, else 0.
__global__ void rotor_norm_kernel(const float* __restrict__ rotor,
                                  unsigned short* __restrict__ rnbT) {
    __shared__ float inv[32];
    const int t = threadIdx.x;            // 64 threads
    if (t < 32) {
        float s = 0.f;
        if (t < ALPHA) {
            #pragma unroll
            for (int j = 0; j < ALPHA; ++j) {
                float v = rotor[t * ALPHA + j];
                s += v * v;
            }
            inv[t] = 1.0f / sqrtf(s);
        } else {
            inv[t] = 0.f;
        }
    }
    __syncthreads();
    const int n  = t >> 1;                // 0..31
    const int k0 = (t & 1) * 16;          // 0 or 16
    #pragma unroll
    for (int kk = 0; kk < 16; ++kk) {
        const int k = k0 + kk;
        float v = (k < ALPHA && n < ALPHA) ? rotor[k * ALPHA + n] * inv[k] : 0.f;
        rnbT[n * 32 + k] = f2bf(v);
    }
}

// The untested 2x2 cell: DMA staging (global_load_lds -- the regime with
// bit-exact ideal WRITE_SIZE and input-L3 residency) + DPP in-register
// softmax (cuts visible LDS ops/wave-tile ~123 -> ~71). Hypothesis: the
// DMA regime's 2.45 TB/s cap is LDS-write-port contention between the DMA
// engine and the ds-op storm; relieving the epilogue raises DMA bw at
// ideal traffic. Skeleton = R3's proven persistent/dbuf/vmcnt(7) loop.
// All LDS regions wave-private: barrier-free.
__global__ __launch_bounds__(TPB, 3) void rotor_main(
        const float* __restrict__ x,
        const unsigned short* __restrict__ rnbT,
        float* __restrict__ out,
        int ntiles) {
    __shared__ float stage[2 * BUFF];     // 53248 B -> 3 blocks/CU

    const int tid  = threadIdx.x;
    const int lane = tid & 63;
    const int wave = tid >> 6;
    const int n15  = lane & 15;
    const int quad = lane >> 4;
    const int waveF = wave * WAVEF;

    // ---- B fragments: two contiguous 16B loads from transposed rnbT ----
    // B-operand layout (16x16x32): n = lane&15, k = quad*8 + j.
    short8 bf0 = *(const short8*)(rnbT + n15 * 32 + quad * 8);
    short8 bf1 = *(const short8*)(rnbT + (n15 + 16) * 32 + quad * 8);

    int tile = blockIdx.x;
    if (tile >= ntiles) return;
    const int stride = gridDim.x;

    // Exactly 8 VMEM ops per tile prefetch, all direct-to-LDS.
    auto prefetch = [&](int buf, int t) {
        const float* gp = x + (long long)t * (TPB * ALPHA) + waveF;
        lds_f* lp = (lds_f*)&stage[buf * BUFF + waveF];
        #pragma unroll
        for (int it = 0; it < 6; ++it)
            __builtin_amdgcn_global_load_lds((glb_f*)(gp + it * 256 + lane * 4),
                                             lp + it * 256, 16, 0, 0);
        __builtin_amdgcn_global_load_lds((glb_f*)(gp + 1536 + lane), lp + 1536, 4, 0, 0);
        __builtin_amdgcn_global_load_lds((glb_f*)(gp + 1600 + lane), lp + 1600, 4, 0, 0);
    };

    prefetch(0, tile);

    int i = 0;
    for (; tile < ntiles; tile += stride, ++i) {
        // Wait for THIS tile's 8 loads (issue order: P(i) 8 ops, then the
        // 7 stores of tile i-1; in-order retirement => vmcnt(7) proves all
        // of P(i) landed while stores may ride on). R3-proven.
        if (i == 0) asm volatile("s_waitcnt vmcnt(0)" ::: "memory");
        else        asm volatile("s_waitcnt vmcnt(7)" ::: "memory");

        const int cur = i & 1;
        const int tnext = tile + stride;
        if (tnext < ntiles) prefetch(cur ^ 1, tnext);
        // Zero-instruction fence: keeps this iteration's stores below the
        // prefetch in issue order (vmcnt accounting depends on it).
        asm volatile("" ::: "memory");

        const int sbase   = cur * BUFF + waveF;
        const int tokBase = tile * TPB + wave * 64;

        // ---- GEMM: 4 M-tiles x 2 N-tiles of mfma_f32_16x16x32_bf16 ----
        float4v accA[4], accB[4];
        #pragma unroll
        for (int m = 0; m < 4; ++m) {
            accA[m] = (float4v){0.f, 0.f, 0.f, 0.f};
            accB[m] = (float4v){0.f, 0.f, 0.f, 0.f};
        }

        #pragma unroll
        for (int m = 0; m < 4; ++m) {
            // A layout: this lane supplies token m*16 + n15, k = quad*8 + j.
            const int tok = tokBase + m * 16 + n15;
            const int r_ = (tok & 8191) % 26;         // S = 8192, position == 1
            const int rowOff = sbase + (m * 16 + n15) * ROWF;
            const int k0 = quad * 8;
            int idx0 = k0 - r_; if (idx0 < 0) idx0 += 26;   // in [0,25]

            short8 af;
            #pragma unroll
            for (int j = 0; j < 8; ++j) {
                int idx = idx0 + j; if (idx >= 26) idx -= 26;  // stays in [0,25]
                // No K-pad mask needed: rnbT rows k>=26 are exact zeros.
                af[j] = (short)f2bf(stage[rowOff + idx]);
            }
            accA[m] = __builtin_amdgcn_mfma_f32_16x16x32_bf16(af, bf0, accA[m], 0, 0, 0);
            accB[m] = __builtin_amdgcn_mfma_f32_16x16x32_bf16(af, bf1, accB[m], 0, 0, 0);
        }

        // ---- In-register softmax (DPP rotate-reduce over the 16-lane row).
        // Lane (n15,quad) holds token m*16+quad*4+rg, features n15 / n15+16.
        // Padded cols 26..31 are exact zeros: excluded from sum; max(real,0)
        // leaves softmax invariant. Scatter results to wave-private LDS
        // (2-way bank aliasing only = free), then stream out coalesced.
        #pragma unroll
        for (int m = 0; m < 4; ++m) {
            #pragma unroll
            for (int rg = 0; rg < 4; ++rg) {
                float a = accA[m][rg];
                float b = accB[m][rg];
                float mx = fmaxf(a, b);
                mx = fmaxf(mx, rorf<0x121>(mx));
                mx = fmaxf(mx, rorf<0x122>(mx));
                mx = fmaxf(mx, rorf<0x124>(mx));
                mx = fmaxf(mx, rorf<0x128>(mx));
                float ea = __expf(a - mx);
                float eb = (n15 < ALPHA - 16) ? __expf(b - mx) : 0.f;
                float s = ea + eb;
                s += rorf<0x121>(s);
                s += rorf<0x122>(s);
                s += rorf<0x124>(s);
                s += rorf<0x128>(s);
                float inv = 1.0f / s;
                const int base = sbase + (m * 16 + quad * 4 + rg) * ROWF;
                stage[base + n15] = ea * inv;
                if (n15 < ALPHA - 16)
                    stage[base + 16 + n15] = eb * inv;
            }
        }

        // ---- Coalesced plain stores (the R0-proven ideal-WRITE path) ----
        float* gout = out + (long long)tile * (TPB * ALPHA) + waveF;
        #pragma unroll
        for (int it = 0; it < 6; ++it) {
            float4 d = *(const float4*)&stage[sbase + it * 256 + lane * 4];
            *(float4*)(gout + it * 256 + lane * 4) = d;
        }
        {
            float2 d = *(const float2*)&stage[sbase + 1536 + lane * 2];
            *(float2*)(gout + 1536 + lane * 2) = d;
        }
    }
}

extern "C" void kernel_launch(void* const* d_in, const int* in_sizes, int n_in,
                              void* d_out, int out_size, void* d_ws, size_t ws_size,
                              hipStream_t stream) {
    const float* x     = (const float*)d_in[0];   // [128, 8192, 26] fp32
    const float* rotor = (const float*)d_in[1];   // [26, 26] fp32
    float* out = (float*)d_out;                   // [128, 8192, 26] fp32
    unsigned short* rnbT = (unsigned short*)d_ws; // bf16 B^T matrix, 32x32 = 2 KB

    rotor_norm_kernel<<<1, 64, 0, stream>>>(rotor, rnbT);

    const int tokens = out_size / ALPHA;          // 1,048,576
    const int tiles  = tokens / TPB;              // 4096
    const int grid   = (tiles < NBLK) ? tiles : NBLK;
    rotor_main<<<grid, TPB, 0, stream>>>(x, rnbT, out, tiles);
}